// Round 15
// baseline (224.524 us; speedup 1.0000x reference)
//
#include <hip/hip_runtime.h>
#include <hip/hip_bf16.h>
#include <stdint.h>

typedef short bf16x8 __attribute__((ext_vector_type(8)));
typedef float f32x4 __attribute__((ext_vector_type(4)));

__device__ __forceinline__ unsigned short f2bf(float f) {
  union { float f; unsigned int u; } v;
  v.f = f;
  unsigned int u = v.u;
  u = (u + 0x7fffu + ((u >> 16) & 1u)) >> 16;  // RNE
  return (unsigned short)u;
}

// HW packed f32->bf16 RNE conversion (bit-identical to f2bf).
__device__ __forceinline__ unsigned int cvt_pk_bf16(float lo, float hi) {
  unsigned int r;
  asm("v_cvt_pk_bf16_f32 %0, %1, %2" : "=v"(r) : "v"(lo), "v"(hi));
  return r;
}

typedef union { bf16x8 v; unsigned int u[4]; } frag_u;

// global->LDS async copy, 16B per lane.
__device__ __forceinline__ void gload16(const void* g, void* lds) {
  __builtin_amdgcn_global_load_lds(
      (const __attribute__((address_space(1))) unsigned int*)(unsigned long long)g,
      (__attribute__((address_space(3))) unsigned int*)(unsigned long long)(unsigned)(unsigned long long)lds,
      16, 0, 0);
}

__device__ __forceinline__ bf16x8 lds_frag(const unsigned short* t, int row, int ch4q) {
  return *(const bf16x8*)(t + row * 64 + ((ch4q ^ (row & 7)) << 3));
}

// Fragment layouts (element = short unless noted):
//  Qfrag/Kfrag[b][t16][h][sub][lane]: ((b*64+t16)*8192) + h*1024 + sub*512 + lane*8
//  Vfrag PAIRED [b][h][ktp][dm][lane][8]: (b*8+h)*65536 + (ktp*4+dm)*512 + lane*8

// ---------------------------------------------------------------------------
// Kernel 1: prep — x -> bf16 (blocks 0..255 first), weights -> transposed bf16.
// ---------------------------------------------------------------------------
__global__ __launch_bounds__(256) void prep_kernel(
    const float* __restrict__ x,
    const float* __restrict__ Wq, const float* __restrict__ Wk, const float* __restrict__ Wv,
    const float* __restrict__ Wfh, const float* __restrict__ Wfg,
    const float* __restrict__ Wrh, const float* __restrict__ Wrg,
    unsigned short* __restrict__ xb, unsigned short* __restrict__ wt) {
  int bid = blockIdx.x;
  int tid = threadIdx.x;
  if (bid < 256) {
    const float4* xi = (const float4*)x;
#pragma unroll
    for (int rep = 0; rep < 8; rep++) {
      int i = bid * 256 + tid + rep * 65536;
      float4 v = xi[i];
      uint2 u;
      u.x = cvt_pk_bf16(v.x, v.y);
      u.y = cvt_pk_bf16(v.z, v.w);
      *(uint2*)&xb[(size_t)i * 4] = u;
    }
  } else {
    __shared__ float tile[64][65];
    int t = bid - 256;
    int mat = t >> 6;
    t &= 63;
    int tr = (t >> 3) * 64, tc = (t & 7) * 64;
    const float* W = (mat == 0) ? Wq : (mat == 1) ? Wk : (mat == 2) ? Wv
                   : (mat == 3) ? Wfh : (mat == 4) ? Wfg : (mat == 5) ? Wrh : Wrg;
    unsigned short* Wt = wt + (size_t)mat * 512 * 512;
    for (int rep = 0; rep < 16; rep++) {
      int idx = rep * 256 + tid;
      int r = idx >> 6, c = idx & 63;
      tile[r][c] = W[(tr + r) * 512 + tc + c];
    }
    __syncthreads();
    for (int rep = 0; rep < 16; rep++) {
      int idx = rep * 256 + tid;
      int r = idx >> 6, c = idx & 63;
      Wt[(tc + r) * 512 + tr + c] = f2bf(tile[c][r]);
    }
  }
}

// ---------------------------------------------------------------------------
// Kernel 2: QKV projection — DOUBLE-BUFFERED staging (unchanged from R13).
// ---------------------------------------------------------------------------
__global__ __launch_bounds__(256, 2) void qkv_kernel(
    const unsigned short* __restrict__ xb,
    const unsigned short* __restrict__ wtq, const unsigned short* __restrict__ wtk,
    const unsigned short* __restrict__ wtv,
    const float* __restrict__ bq, const float* __restrict__ bk, const float* __restrict__ bv,
    unsigned short* __restrict__ Qfrag, unsigned short* __restrict__ Kfrag,
    unsigned short* __restrict__ Vfrag) {
  __shared__ __attribute__((aligned(16))) unsigned short smem[32768];  // 64 KB
  // buffer layout (shorts, per 16384-short buffer): As=+0 Bq=+4096 Bk=+8192 Bv=+12288
  unsigned short* st0 = smem;                // [64*72] each, epilogue only
  unsigned short* st1 = smem + 4608;
  unsigned short* st2 = smem + 9216;
  const int m0 = blockIdx.y * 64, n0 = blockIdx.x * 64;
  const int tid = threadIdx.x, w = tid >> 6, lane = tid & 63;
  const int c = lane & 15, quad = lane >> 4;
  const int wm = w & 1, wn = w >> 1;
  const int rsel = lane >> 3, csel = lane & 7;
  const int sc = csel ^ rsel;
  const char* Ag  = (const char*)xb  + (size_t)(m0 + w * 16 + rsel) * 1024 + sc * 16;
  const char* Bgq = (const char*)wtq + (size_t)(n0 + w * 16 + rsel) * 1024 + sc * 16;
  const char* Bgk = (const char*)wtk + (size_t)(n0 + w * 16 + rsel) * 1024 + sc * 16;
  const char* Bgv = (const char*)wtv + (size_t)(n0 + w * 16 + rsel) * 1024 + sc * 16;
  const int woff = w * 1024;

  f32x4 acc[3][2][2];
  f32x4 z4 = {0.f, 0.f, 0.f, 0.f};
#pragma unroll
  for (int o = 0; o < 3; o++)
#pragma unroll
    for (int i = 0; i < 2; i++)
#pragma unroll
      for (int j = 0; j < 2; j++) acc[o][i][j] = z4;

  // prologue: stage ks=0 into buf0
  {
    unsigned short* base = smem;
    gload16(Ag, base + woff);              gload16(Ag + 8192, base + woff + 512);
    gload16(Bgq, base + 4096 + woff);      gload16(Bgq + 8192, base + 4096 + woff + 512);
    gload16(Bgk, base + 8192 + woff);      gload16(Bgk + 8192, base + 8192 + woff + 512);
    gload16(Bgv, base + 12288 + woff);     gload16(Bgv + 8192, base + 12288 + woff + 512);
  }
  __syncthreads();

  for (int ks = 0; ks < 8; ks++) {
    unsigned short* cur = smem + (ks & 1) * 16384;
    if (ks < 7) {
      unsigned short* nxt = smem + ((ks + 1) & 1) * 16384;
      const int kb = (ks + 1) * 128;
      gload16(Ag + kb, nxt + woff);          gload16(Ag + kb + 8192, nxt + woff + 512);
      gload16(Bgq + kb, nxt + 4096 + woff);  gload16(Bgq + kb + 8192, nxt + 4096 + woff + 512);
      gload16(Bgk + kb, nxt + 8192 + woff);  gload16(Bgk + kb + 8192, nxt + 8192 + woff + 512);
      gload16(Bgv + kb, nxt + 12288 + woff); gload16(Bgv + kb + 8192, nxt + 12288 + woff + 512);
    }
#pragma unroll
    for (int ch = 0; ch < 2; ch++) {
      const int cq = ch * 4 + quad;
      bf16x8 a0 = lds_frag(cur, wm * 32 + c, cq);
      bf16x8 a1 = lds_frag(cur, wm * 32 + 16 + c, cq);
#pragma unroll
      for (int nt = 0; nt < 2; nt++) {
        const int rb = wn * 32 + nt * 16 + c;
        bf16x8 fq = lds_frag(cur + 4096, rb, cq);
        bf16x8 fk = lds_frag(cur + 8192, rb, cq);
        bf16x8 fv = lds_frag(cur + 12288, rb, cq);
        acc[0][0][nt] = __builtin_amdgcn_mfma_f32_16x16x32_bf16(a0, fq, acc[0][0][nt], 0, 0, 0);
        acc[0][1][nt] = __builtin_amdgcn_mfma_f32_16x16x32_bf16(a1, fq, acc[0][1][nt], 0, 0, 0);
        acc[1][0][nt] = __builtin_amdgcn_mfma_f32_16x16x32_bf16(a0, fk, acc[1][0][nt], 0, 0, 0);
        acc[1][1][nt] = __builtin_amdgcn_mfma_f32_16x16x32_bf16(a1, fk, acc[1][1][nt], 0, 0, 0);
        acc[2][0][nt] = __builtin_amdgcn_mfma_f32_16x16x32_bf16(a0, fv, acc[2][0][nt], 0, 0, 0);
        acc[2][1][nt] = __builtin_amdgcn_mfma_f32_16x16x32_bf16(a1, fv, acc[2][1][nt], 0, 0, 0);
      }
    }
    __syncthreads();  // drains next-tile DMA + guards cur reuse
  }

  // stage: st0=Q[t][d], st1=K[t][d], st2=V[d][t]  (st unions over buf0, dead)
#pragma unroll
  for (int ms = 0; ms < 2; ms++)
#pragma unroll
    for (int nt = 0; nt < 2; nt++) {
      int n_l = wn * 32 + nt * 16 + c;
      int n = n0 + n_l;
      float biasq = bq[n], biask = bk[n], biasv = bv[n];
#pragma unroll
      for (int r = 0; r < 4; r++) {
        int m_l = wm * 32 + ms * 16 + quad * 4 + r;
        st0[m_l * 72 + n_l] = f2bf((acc[0][ms][nt][r] + biasq) * 0.125f);
        st1[m_l * 72 + n_l] = f2bf(acc[1][ms][nt][r] + biask);
        st2[n_l * 72 + m_l] = f2bf(acc[2][ms][nt][r] + biasv);
      }
    }
  __syncthreads();

  {
    const int h = n0 >> 6;
    const int bb = m0 >> 10, t0b = (m0 & 1023) >> 4;
#pragma unroll
    for (int sub = 0; sub < 2; sub++) {
      uint4 vq = *(uint4*)&st0[(w * 16 + c) * 72 + sub * 32 + quad * 8];
      uint4 vk = *(uint4*)&st1[(w * 16 + c) * 72 + sub * 32 + quad * 8];
      size_t base = (size_t)((bb * 64 + t0b + w) * 8192) + h * 1024 + sub * 512 + lane * 8;
      *(uint4*)&Qfrag[base] = vq;
      *(uint4*)&Kfrag[base] = vk;
    }
    // pair-packed V fragments: kt = t0b + w; half = kt&1 selects shorts 0..3/4..7
    const int ktq = t0b + w;
    const int ktp = ktq >> 1, half = ktq & 1;
#pragma unroll
    for (int dm = 0; dm < 4; dm++) {
      uint2 vv = *(uint2*)&st2[(dm * 16 + c) * 72 + w * 16 + quad * 4];
      size_t base = (size_t)(bb * 8 + h) * 65536 + (size_t)(ktp * 4 + dm) * 512
                  + lane * 8 + half * 4;
      *(uint2*)&Vfrag[base] = vv;
    }
  }
}

// ---------------------------------------------------------------------------
// Kernel 3: attn — FUSED zgate + pv + FINAL GEMM.
// Phases 1-2: EXACT R9/R13 body (frozen; 56us, VGPR 64 in isolation), except
// phase-2 output goes to LDS ts[2][16][520] (padded rows: 2-way-free banks)
// instead of global Tfb/Trb.
// EPILOGUE (new): block (b,qt) holds complete 16 rows of T_f/T_r in ts.
// Wave w computes out cols w*64..w*64+63: K=512 loop, A-frags from ts,
// B-frags streamed from the transposed weights (2MB, L2-hot across all
// 256 blocks), 16 MFMA per 32-k step, then bias+sigmoid-gate combine to
// out. Replaces the entire final kernel + 8MB Tfb/Trb round-trip.
// ---------------------------------------------------------------------------
__global__ __launch_bounds__(512, 2) void attn_kernel(
    const unsigned short* __restrict__ Qfrag, const unsigned short* __restrict__ Kfrag,
    const unsigned short* __restrict__ Vfrag,
    const float* __restrict__ conv_w, const float* __restrict__ conv_b,
    const unsigned short* __restrict__ wfh, const unsigned short* __restrict__ wfg,
    const unsigned short* __restrict__ wrh, const unsigned short* __restrict__ wrg,
    const float* __restrict__ bfh, const float* __restrict__ bfg,
    const float* __restrict__ brh, const float* __restrict__ brg,
    float* __restrict__ out) {
  const int b = blockIdx.x, qt = blockIdx.y;
  const int tid = threadIdx.x, w = tid >> 6, lane = tid & 63;
  const int c = lane & 15, quad = lane >> 4;
  __shared__ float zbuf[8][16];
  __shared__ float izbuf[8][16];
  __shared__ __attribute__((aligned(16))) float red[2 * 8 * 4 * 64 * 4];  // 64 KB
  __shared__ float zred[2][8][16];
  __shared__ __attribute__((aligned(16))) unsigned short ts[2][16][520];  // 33 KB

  f32x4 z4 = {0.f, 0.f, 0.f, 0.f};
  const float cb = conv_b[0];
  const size_t qbase = (size_t)((b * 64 + qt) * 8192) + lane * 8;
  const size_t kb0 = (size_t)((b * 64 + w * 8) * 8192) + lane * 8;
  const size_t vb0 = (size_t)(b * 8) * 65536 + lane * 8;  // + h*65536

  f32x4 g[8];
#pragma unroll
  for (int j = 0; j < 8; j++) g[j] = {cb, cb, cb, cb};

  // ---------------- phase 1: Z + gate logits ----------------
  for (int h = 0; h < 8; h++) {
    bf16x8 qf0 = *(const bf16x8*)&Qfrag[qbase + h * 1024];
    bf16x8 qf1 = *(const bf16x8*)&Qfrag[qbase + h * 1024 + 512];
    f32x4 p[8];
    float zh = 0.f;
#pragma unroll
    for (int j = 0; j < 8; j++) {
      const size_t kb = kb0 + (size_t)j * 8192 + h * 1024;
      bf16x8 kf0 = *(const bf16x8*)&Kfrag[kb];
      bf16x8 kf1 = *(const bf16x8*)&Kfrag[kb + 512];
      f32x4 s = __builtin_amdgcn_mfma_f32_16x16x32_bf16(kf0, qf0, z4, 0, 0, 0);
      s = __builtin_amdgcn_mfma_f32_16x16x32_bf16(kf1, qf1, s, 0, 0, 0);
      p[j][0] = __expf(s[0]); p[j][1] = __expf(s[1]);
      p[j][2] = __expf(s[2]); p[j][3] = __expf(s[3]);
      zh += (p[j][0] + p[j][1]) + (p[j][2] + p[j][3]);
    }
    zh += __shfl_xor(zh, 16); zh += __shfl_xor(zh, 32);
    __syncthreads();                 // prev h's zbuf reads complete
    if (quad == 0) zbuf[w][c] = zh;
    __syncthreads();                 // all wave partials visible
    float Z = ((zbuf[0][c] + zbuf[1][c]) + (zbuf[2][c] + zbuf[3][c]))
            + ((zbuf[4][c] + zbuf[5][c]) + (zbuf[6][c] + zbuf[7][c]));
    const float izq = 1.0f / Z;
    if (w == 0 && quad == 0) izbuf[h][c] = izq;
    const float cwz = conv_w[h] * izq;
#pragma unroll
    for (int j = 0; j < 8; j++) {
      g[j][0] += cwz * p[j][0]; g[j][1] += cwz * p[j][1];
      g[j][2] += cwz * p[j][2]; g[j][3] += cwz * p[j][3];
    }
  }

  // masks: bit(8r) = M_f (logit<=0), bit(8r+1) = M_r (logit>=0)
  unsigned int mmx[4], mmy[4];
#pragma unroll
  for (int t = 0; t < 4; t++) {
    unsigned int p0 = 0, p1 = 0;
#pragma unroll
    for (int r = 0; r < 4; r++) {
      p0 |= ((g[2 * t][r] <= 0.f ? 1u : 0u) | (g[2 * t][r] >= 0.f ? 2u : 0u)) << (8 * r);
      p1 |= ((g[2 * t + 1][r] <= 0.f ? 1u : 0u) | (g[2 * t + 1][r] >= 0.f ? 2u : 0u)) << (8 * r);
    }
    mmx[t] = p0; mmy[t] = p1;
  }
  __syncthreads();  // izbuf visible to all threads before phase 2

  frag_u ones;
  ones.u[0] = 0x3F803F80u; ones.u[1] = 0x3F803F80u;
  ones.u[2] = 0x3F803F80u; ones.u[3] = 0x3F803F80u;

  const int fr = w >> 2, dmslot = w & 3;

  // ---------------- phase 2: PV with recompute ----------------
  for (int h = 0; h < 8; h++) {
    bf16x8 qf0 = *(const bf16x8*)&Qfrag[qbase + h * 1024];
    bf16x8 qf1 = *(const bf16x8*)&Qfrag[qbase + h * 1024 + 512];
    const float iz_h = izbuf[h][c];
    f32x4 accf[4], accr[4];
#pragma unroll
    for (int i = 0; i < 4; i++) { accf[i] = z4; accr[i] = z4; }
    f32x4 zf4 = z4, zr4 = z4;
#pragma unroll
    for (int t = 0; t < 4; t++) {
      const size_t kba = kb0 + (size_t)(2 * t) * 8192 + h * 1024;
      const size_t kbb = kba + 8192;
      bf16x8 ka0 = *(const bf16x8*)&Kfrag[kba];
      bf16x8 ka1 = *(const bf16x8*)&Kfrag[kba + 512];
      bf16x8 kb0f = *(const bf16x8*)&Kfrag[kbb];
      bf16x8 kb1f = *(const bf16x8*)&Kfrag[kbb + 512];
      f32x4 sa = __builtin_amdgcn_mfma_f32_16x16x32_bf16(ka0, qf0, z4, 0, 0, 0);
      sa = __builtin_amdgcn_mfma_f32_16x16x32_bf16(ka1, qf1, sa, 0, 0, 0);
      f32x4 sb = __builtin_amdgcn_mfma_f32_16x16x32_bf16(kb0f, qf0, z4, 0, 0, 0);
      sb = __builtin_amdgcn_mfma_f32_16x16x32_bf16(kb1f, qf1, sb, 0, 0, 0);
      float ea[4], eb[4];
#pragma unroll
      for (int r = 0; r < 4; r++) {
        ea[r] = __expf(__expf(sa[r]) * iz_h);
        eb[r] = __expf(__expf(sb[r]) * iz_h);
      }
      frag_u pF, pR;
      pF.u[0] = cvt_pk_bf16((mmx[t] & 0x1u)       ? ea[0] : 1.f, (mmx[t] & 0x100u)     ? ea[1] : 1.f);
      pF.u[1] = cvt_pk_bf16((mmx[t] & 0x10000u)   ? ea[2] : 1.f, (mmx[t] & 0x1000000u) ? ea[3] : 1.f);
      pF.u[2] = cvt_pk_bf16((mmy[t] & 0x1u)       ? eb[0] : 1.f, (mmy[t] & 0x100u)     ? eb[1] : 1.f);
      pF.u[3] = cvt_pk_bf16((mmy[t] & 0x10000u)   ? eb[2] : 1.f, (mmy[t] & 0x1000000u) ? eb[3] : 1.f);
      pR.u[0] = cvt_pk_bf16((mmx[t] & 0x2u)       ? ea[0] : 1.f, (mmx[t] & 0x200u)     ? ea[1] : 1.f);
      pR.u[1] = cvt_pk_bf16((mmx[t] & 0x20000u)   ? ea[2] : 1.f, (mmx[t] & 0x2000000u) ? ea[3] : 1.f);
      pR.u[2] = cvt_pk_bf16((mmy[t] & 0x2u)       ? eb[0] : 1.f, (mmy[t] & 0x200u)     ? eb[1] : 1.f);
      pR.u[3] = cvt_pk_bf16((mmy[t] & 0x20000u)   ? eb[2] : 1.f, (mmy[t] & 0x2000000u) ? eb[3] : 1.f);
      zf4 = __builtin_amdgcn_mfma_f32_16x16x32_bf16(ones.v, pF.v, zf4, 0, 0, 0);
      zr4 = __builtin_amdgcn_mfma_f32_16x16x32_bf16(ones.v, pR.v, zr4, 0, 0, 0);
      const size_t vbh = vb0 + (size_t)h * 65536 + (size_t)((w * 4 + t) * 4) * 512;
#pragma unroll
      for (int dm = 0; dm < 4; dm++) {
        bf16x8 vf = *(const bf16x8*)&Vfrag[vbh + (size_t)dm * 512];
        accf[dm] = __builtin_amdgcn_mfma_f32_16x16x32_bf16(vf, pF.v, accf[dm], 0, 0, 0);
        accr[dm] = __builtin_amdgcn_mfma_f32_16x16x32_bf16(vf, pR.v, accr[dm], 0, 0, 0);
      }
    }
    // cross-wave reduce: all waves write their partials, slot waves combine
    __syncthreads();   // prev h's slot reads complete
#pragma unroll
    for (int dm = 0; dm < 4; dm++) {
      *(f32x4*)&red[(((0 * 8 + w) * 4 + dm) * 64 + lane) * 4] = accf[dm];
      *(f32x4*)&red[(((1 * 8 + w) * 4 + dm) * 64 + lane) * 4] = accr[dm];
    }
    if (quad == 0) { zred[0][w][c] = zf4[0]; zred[1][w][c] = zr4[0]; }
    __syncthreads();
    {
      f32x4 o = z4;
#pragma unroll
      for (int w2 = 0; w2 < 8; w2++)
        o += *(const f32x4*)&red[(((fr * 8 + w2) * 4 + dmslot) * 64 + lane) * 4];
      float Zq = 0.f;
#pragma unroll
      for (int w2 = 0; w2 < 8; w2++) Zq += zred[fr][w2][c];
      const float iz = 1.0f / Zq;
      uint2 u;
      u.x = cvt_pk_bf16(o[0] * iz, o[1] * iz);
      u.y = cvt_pk_bf16(o[2] * iz, o[3] * iz);
      *(uint2*)&ts[fr][c][h * 64 + dmslot * 16 + quad * 4] = u;
    }
  }
  __syncthreads();  // all of ts visible to all waves

  // ---------------- epilogue: fused final 4-GEMM + gate combine ----------
  // wave w owns out cols n0w..n0w+63 for the block's 16 rows.
  {
    const int n0w = w * 64;
    const size_t r0 = (size_t)(b * 1024 + qt * 16);
    f32x4 oa[4][4];  // [mat][nt]
#pragma unroll
    for (int o = 0; o < 4; o++)
#pragma unroll
      for (int j = 0; j < 4; j++) oa[o][j] = z4;

    for (int kk = 0; kk < 512; kk += 32) {
      const int ko = kk + quad * 8;
      bf16x8 aF = *(const bf16x8*)&ts[0][c][ko];
      bf16x8 aR = *(const bf16x8*)&ts[1][c][ko];
#pragma unroll
      for (int nt = 0; nt < 4; nt++) {
        const size_t bo = (size_t)(n0w + nt * 16 + c) * 512 + ko;
        bf16x8 b0 = *(const bf16x8*)&wfh[bo];
        bf16x8 b1 = *(const bf16x8*)&wfg[bo];
        bf16x8 b2 = *(const bf16x8*)&wrh[bo];
        bf16x8 b3 = *(const bf16x8*)&wrg[bo];
        oa[0][nt] = __builtin_amdgcn_mfma_f32_16x16x32_bf16(aF, b0, oa[0][nt], 0, 0, 0);
        oa[1][nt] = __builtin_amdgcn_mfma_f32_16x16x32_bf16(aF, b1, oa[1][nt], 0, 0, 0);
        oa[2][nt] = __builtin_amdgcn_mfma_f32_16x16x32_bf16(aR, b2, oa[2][nt], 0, 0, 0);
        oa[3][nt] = __builtin_amdgcn_mfma_f32_16x16x32_bf16(aR, b3, oa[3][nt], 0, 0, 0);
      }
    }

#pragma unroll
    for (int nt = 0; nt < 4; nt++) {
      int n = n0w + nt * 16 + c;
      float b0 = bfh[n], b1 = bfg[n], b2 = brh[n], b3 = brg[n];
#pragma unroll
      for (int r = 0; r < 4; r++) {
        size_t t = r0 + quad * 4 + r;
        float Ff = oa[0][nt][r] + b0;
        float Gf = 1.0f / (1.0f + __expf(-(oa[1][nt][r] + b1)));
        float Fr = oa[2][nt][r] + b2;
        float Gr = 1.0f / (1.0f + __expf(-(oa[3][nt][r] + b3)));
        float ef = __expf(Gf), er = __expf(Gr);
        out[t * 512 + n] = (Ff * ef + Fr * er) / (ef + er);
      }
    }
  }
}

// ---------------------------------------------------------------------------
// Launch. Workspace (bytes):
//   0: xb 4MB | 4: Qfrag 4MB | 8: Kfrag 4MB | 12: Vfrag 4MB | 24: wt 3.5MB
// ---------------------------------------------------------------------------
extern "C" void kernel_launch(void* const* d_in, const int* in_sizes, int n_in,
                              void* d_out, int out_size, void* d_ws, size_t ws_size,
                              hipStream_t stream) {
  const float* x   = (const float*)d_in[0];
  const float* Wq  = (const float*)d_in[1];
  const float* bq  = (const float*)d_in[2];
  const float* Wk  = (const float*)d_in[3];
  const float* bk  = (const float*)d_in[4];
  const float* Wv  = (const float*)d_in[5];
  const float* bv  = (const float*)d_in[6];
  const float* cw  = (const float*)d_in[7];
  const float* cb  = (const float*)d_in[8];
  const float* Wfh = (const float*)d_in[9];
  const float* bfh = (const float*)d_in[10];
  const float* Wfg = (const float*)d_in[11];
  const float* bfg = (const float*)d_in[12];
  const float* Wrh = (const float*)d_in[13];
  const float* brh = (const float*)d_in[14];
  const float* Wrg = (const float*)d_in[15];
  const float* brg = (const float*)d_in[16];

  char* ws = (char*)d_ws;
  const size_t MB = 1024 * 1024;
  unsigned short* xb    = (unsigned short*)(ws + 0 * MB);
  unsigned short* Qfrag = (unsigned short*)(ws + 4 * MB);
  unsigned short* Kfrag = (unsigned short*)(ws + 8 * MB);
  unsigned short* Vfrag = (unsigned short*)(ws + 12 * MB);
  unsigned short* wt    = (unsigned short*)(ws + 24 * MB);
  const size_t WSZ = 512 * 512;

  prep_kernel<<<704, 256, 0, stream>>>(x, Wq, Wk, Wv, Wfh, Wfg, Wrh, Wrg, xb, wt);
  qkv_kernel<<<dim3(8, 64), 256, 0, stream>>>(xb, wt + 0 * WSZ, wt + 1 * WSZ, wt + 2 * WSZ,
                                              bq, bk, bv, Qfrag, Kfrag, Vfrag);
  attn_kernel<<<dim3(4, 64), 512, 0, stream>>>(Qfrag, Kfrag, Vfrag, cw, cb,
                                               wt + 3 * WSZ, wt + 4 * WSZ,
                                               wt + 5 * WSZ, wt + 6 * WSZ,
                                               bfh, bfg, brh, brg, (float*)d_out);
}

// Round 16
// 174.467 us; speedup vs baseline: 1.2869x; 1.2869x over previous
//
#include <hip/hip_runtime.h>
#include <hip/hip_bf16.h>
#include <stdint.h>

typedef short bf16x8 __attribute__((ext_vector_type(8)));
typedef float f32x4 __attribute__((ext_vector_type(4)));

__device__ __forceinline__ unsigned short f2bf(float f) {
  union { float f; unsigned int u; } v;
  v.f = f;
  unsigned int u = v.u;
  u = (u + 0x7fffu + ((u >> 16) & 1u)) >> 16;  // RNE
  return (unsigned short)u;
}

// HW packed f32->bf16 RNE conversion (bit-identical to f2bf).
__device__ __forceinline__ unsigned int cvt_pk_bf16(float lo, float hi) {
  unsigned int r;
  asm("v_cvt_pk_bf16_f32 %0, %1, %2" : "=v"(r) : "v"(lo), "v"(hi));
  return r;
}

typedef union { bf16x8 v; unsigned int u[4]; } frag_u;

// global->LDS async copy, 16B per lane.
__device__ __forceinline__ void gload16(const void* g, void* lds) {
  __builtin_amdgcn_global_load_lds(
      (const __attribute__((address_space(1))) unsigned int*)(unsigned long long)g,
      (__attribute__((address_space(3))) unsigned int*)(unsigned long long)(unsigned)(unsigned long long)lds,
      16, 0, 0);
}

__device__ __forceinline__ bf16x8 lds_frag(const unsigned short* t, int row, int ch4q) {
  return *(const bf16x8*)(t + row * 64 + ((ch4q ^ (row & 7)) << 3));
}

// Fragment layouts (element = short unless noted):
//  Qfrag/Kfrag[b][t16][h][sub][lane]: ((b*64+t16)*8192) + h*1024 + sub*512 + lane*8
//  Vfrag PAIRED [b][h][ktp][dm][lane][8]: (b*8+h)*65536 + (ktp*4+dm)*512 + lane*8

// ---------------------------------------------------------------------------
// Kernel 1: prep — x -> bf16 (blocks 0..255 first), weights -> transposed bf16.
// ---------------------------------------------------------------------------
__global__ __launch_bounds__(256) void prep_kernel(
    const float* __restrict__ x,
    const float* __restrict__ Wq, const float* __restrict__ Wk, const float* __restrict__ Wv,
    const float* __restrict__ Wfh, const float* __restrict__ Wfg,
    const float* __restrict__ Wrh, const float* __restrict__ Wrg,
    unsigned short* __restrict__ xb, unsigned short* __restrict__ wt) {
  int bid = blockIdx.x;
  int tid = threadIdx.x;
  if (bid < 256) {
    const float4* xi = (const float4*)x;
#pragma unroll
    for (int rep = 0; rep < 8; rep++) {
      int i = bid * 256 + tid + rep * 65536;
      float4 v = xi[i];
      uint2 u;
      u.x = cvt_pk_bf16(v.x, v.y);
      u.y = cvt_pk_bf16(v.z, v.w);
      *(uint2*)&xb[(size_t)i * 4] = u;
    }
  } else {
    __shared__ float tile[64][65];
    int t = bid - 256;
    int mat = t >> 6;
    t &= 63;
    int tr = (t >> 3) * 64, tc = (t & 7) * 64;
    const float* W = (mat == 0) ? Wq : (mat == 1) ? Wk : (mat == 2) ? Wv
                   : (mat == 3) ? Wfh : (mat == 4) ? Wfg : (mat == 5) ? Wrh : Wrg;
    unsigned short* Wt = wt + (size_t)mat * 512 * 512;
    for (int rep = 0; rep < 16; rep++) {
      int idx = rep * 256 + tid;
      int r = idx >> 6, c = idx & 63;
      tile[r][c] = W[(tr + r) * 512 + tc + c];
    }
    __syncthreads();
    for (int rep = 0; rep < 16; rep++) {
      int idx = rep * 256 + tid;
      int r = idx >> 6, c = idx & 63;
      Wt[(tc + r) * 512 + tr + c] = f2bf(tile[c][r]);
    }
  }
}

// ---------------------------------------------------------------------------
// Kernel 2: QKV projection — DOUBLE-BUFFERED staging (R13 exact).
// ---------------------------------------------------------------------------
__global__ __launch_bounds__(256, 2) void qkv_kernel(
    const unsigned short* __restrict__ xb,
    const unsigned short* __restrict__ wtq, const unsigned short* __restrict__ wtk,
    const unsigned short* __restrict__ wtv,
    const float* __restrict__ bq, const float* __restrict__ bk, const float* __restrict__ bv,
    unsigned short* __restrict__ Qfrag, unsigned short* __restrict__ Kfrag,
    unsigned short* __restrict__ Vfrag) {
  __shared__ __attribute__((aligned(16))) unsigned short smem[32768];  // 64 KB
  // buffer layout (shorts, per 16384-short buffer): As=+0 Bq=+4096 Bk=+8192 Bv=+12288
  unsigned short* st0 = smem;                // [64*72] each, epilogue only
  unsigned short* st1 = smem + 4608;
  unsigned short* st2 = smem + 9216;
  const int m0 = blockIdx.y * 64, n0 = blockIdx.x * 64;
  const int tid = threadIdx.x, w = tid >> 6, lane = tid & 63;
  const int c = lane & 15, quad = lane >> 4;
  const int wm = w & 1, wn = w >> 1;
  const int rsel = lane >> 3, csel = lane & 7;
  const int sc = csel ^ rsel;
  const char* Ag  = (const char*)xb  + (size_t)(m0 + w * 16 + rsel) * 1024 + sc * 16;
  const char* Bgq = (const char*)wtq + (size_t)(n0 + w * 16 + rsel) * 1024 + sc * 16;
  const char* Bgk = (const char*)wtk + (size_t)(n0 + w * 16 + rsel) * 1024 + sc * 16;
  const char* Bgv = (const char*)wtv + (size_t)(n0 + w * 16 + rsel) * 1024 + sc * 16;
  const int woff = w * 1024;

  f32x4 acc[3][2][2];
  f32x4 z4 = {0.f, 0.f, 0.f, 0.f};
#pragma unroll
  for (int o = 0; o < 3; o++)
#pragma unroll
    for (int i = 0; i < 2; i++)
#pragma unroll
      for (int j = 0; j < 2; j++) acc[o][i][j] = z4;

  // prologue: stage ks=0 into buf0
  {
    unsigned short* base = smem;
    gload16(Ag, base + woff);              gload16(Ag + 8192, base + woff + 512);
    gload16(Bgq, base + 4096 + woff);      gload16(Bgq + 8192, base + 4096 + woff + 512);
    gload16(Bgk, base + 8192 + woff);      gload16(Bgk + 8192, base + 8192 + woff + 512);
    gload16(Bgv, base + 12288 + woff);     gload16(Bgv + 8192, base + 12288 + woff + 512);
  }
  __syncthreads();

  for (int ks = 0; ks < 8; ks++) {
    unsigned short* cur = smem + (ks & 1) * 16384;
    if (ks < 7) {
      unsigned short* nxt = smem + ((ks + 1) & 1) * 16384;
      const int kb = (ks + 1) * 128;
      gload16(Ag + kb, nxt + woff);          gload16(Ag + kb + 8192, nxt + woff + 512);
      gload16(Bgq + kb, nxt + 4096 + woff);  gload16(Bgq + kb + 8192, nxt + 4096 + woff + 512);
      gload16(Bgk + kb, nxt + 8192 + woff);  gload16(Bgk + kb + 8192, nxt + 8192 + woff + 512);
      gload16(Bgv + kb, nxt + 12288 + woff); gload16(Bgv + kb + 8192, nxt + 12288 + woff + 512);
    }
#pragma unroll
    for (int ch = 0; ch < 2; ch++) {
      const int cq = ch * 4 + quad;
      bf16x8 a0 = lds_frag(cur, wm * 32 + c, cq);
      bf16x8 a1 = lds_frag(cur, wm * 32 + 16 + c, cq);
#pragma unroll
      for (int nt = 0; nt < 2; nt++) {
        const int rb = wn * 32 + nt * 16 + c;
        bf16x8 fq = lds_frag(cur + 4096, rb, cq);
        bf16x8 fk = lds_frag(cur + 8192, rb, cq);
        bf16x8 fv = lds_frag(cur + 12288, rb, cq);
        acc[0][0][nt] = __builtin_amdgcn_mfma_f32_16x16x32_bf16(a0, fq, acc[0][0][nt], 0, 0, 0);
        acc[0][1][nt] = __builtin_amdgcn_mfma_f32_16x16x32_bf16(a1, fq, acc[0][1][nt], 0, 0, 0);
        acc[1][0][nt] = __builtin_amdgcn_mfma_f32_16x16x32_bf16(a0, fk, acc[1][0][nt], 0, 0, 0);
        acc[1][1][nt] = __builtin_amdgcn_mfma_f32_16x16x32_bf16(a1, fk, acc[1][1][nt], 0, 0, 0);
        acc[2][0][nt] = __builtin_amdgcn_mfma_f32_16x16x32_bf16(a0, fv, acc[2][0][nt], 0, 0, 0);
        acc[2][1][nt] = __builtin_amdgcn_mfma_f32_16x16x32_bf16(a1, fv, acc[2][1][nt], 0, 0, 0);
      }
    }
    __syncthreads();  // drains next-tile DMA + guards cur reuse
  }

  // stage: st0=Q[t][d], st1=K[t][d], st2=V[d][t]  (st unions over buf0, dead)
#pragma unroll
  for (int ms = 0; ms < 2; ms++)
#pragma unroll
    for (int nt = 0; nt < 2; nt++) {
      int n_l = wn * 32 + nt * 16 + c;
      int n = n0 + n_l;
      float biasq = bq[n], biask = bk[n], biasv = bv[n];
#pragma unroll
      for (int r = 0; r < 4; r++) {
        int m_l = wm * 32 + ms * 16 + quad * 4 + r;
        st0[m_l * 72 + n_l] = f2bf((acc[0][ms][nt][r] + biasq) * 0.125f);
        st1[m_l * 72 + n_l] = f2bf(acc[1][ms][nt][r] + biask);
        st2[n_l * 72 + m_l] = f2bf(acc[2][ms][nt][r] + biasv);
      }
    }
  __syncthreads();

  {
    const int h = n0 >> 6;
    const int bb = m0 >> 10, t0b = (m0 & 1023) >> 4;
#pragma unroll
    for (int sub = 0; sub < 2; sub++) {
      uint4 vq = *(uint4*)&st0[(w * 16 + c) * 72 + sub * 32 + quad * 8];
      uint4 vk = *(uint4*)&st1[(w * 16 + c) * 72 + sub * 32 + quad * 8];
      size_t base = (size_t)((bb * 64 + t0b + w) * 8192) + h * 1024 + sub * 512 + lane * 8;
      *(uint4*)&Qfrag[base] = vq;
      *(uint4*)&Kfrag[base] = vk;
    }
    // pair-packed V fragments: kt = t0b + w; half = kt&1 selects shorts 0..3/4..7
    const int ktq = t0b + w;
    const int ktp = ktq >> 1, half = ktq & 1;
#pragma unroll
    for (int dm = 0; dm < 4; dm++) {
      uint2 vv = *(uint2*)&st2[(dm * 16 + c) * 72 + w * 16 + quad * 4];
      size_t base = (size_t)(bb * 8 + h) * 65536 + (size_t)(ktp * 4 + dm) * 512
                  + lane * 8 + half * 4;
      *(uint2*)&Vfrag[base] = vv;
    }
  }
}

// ---------------------------------------------------------------------------
// Kernel 3: attn — FUSED zgate+pv. EXACT R9/R13 body, FROZEN.
// grid (4 b, 64 qt16), 512 thr = 8 waves; wave w owns kt = 8w..8w+7.
// launch_bounds (512,2): measured VGPR=64, 56.3-56.8us, zero spill.
// DO NOT PERTURB: R6 (1024thr) spilled; R7 (h-pair+wpe) 67us; R8 (P-cache)
// spilled; R11 (wpe alone) 67us @ VGPR 88; R12 (barrier-halving) 67us @
// VGPR 88; R15 (fused final epilogue) 130us @ VGPR 128 + 327K bank
// conflicts. Every deviation from this source shifts codegen off the
// 64-VGPR schedule and costs 11-70us.
// ---------------------------------------------------------------------------
__global__ __launch_bounds__(512, 2) void attn_kernel(
    const unsigned short* __restrict__ Qfrag, const unsigned short* __restrict__ Kfrag,
    const unsigned short* __restrict__ Vfrag,
    const float* __restrict__ conv_w, const float* __restrict__ conv_b,
    unsigned short* __restrict__ Tfb, unsigned short* __restrict__ Trb) {
  const int b = blockIdx.x, qt = blockIdx.y;
  const int tid = threadIdx.x, w = tid >> 6, lane = tid & 63;
  const int c = lane & 15, quad = lane >> 4;
  __shared__ float zbuf[8][16];
  __shared__ float izbuf[8][16];
  __shared__ __attribute__((aligned(16))) float red[2 * 8 * 4 * 64 * 4];  // 64 KB
  __shared__ float zred[2][8][16];

  f32x4 z4 = {0.f, 0.f, 0.f, 0.f};
  const float cb = conv_b[0];
  const size_t qbase = (size_t)((b * 64 + qt) * 8192) + lane * 8;
  const size_t kb0 = (size_t)((b * 64 + w * 8) * 8192) + lane * 8;
  const size_t vb0 = (size_t)(b * 8) * 65536 + lane * 8;  // + h*65536

  f32x4 g[8];
#pragma unroll
  for (int j = 0; j < 8; j++) g[j] = {cb, cb, cb, cb};

  // ---------------- phase 1: Z + gate logits ----------------
  for (int h = 0; h < 8; h++) {
    bf16x8 qf0 = *(const bf16x8*)&Qfrag[qbase + h * 1024];
    bf16x8 qf1 = *(const bf16x8*)&Qfrag[qbase + h * 1024 + 512];
    f32x4 p[8];
    float zh = 0.f;
#pragma unroll
    for (int j = 0; j < 8; j++) {
      const size_t kb = kb0 + (size_t)j * 8192 + h * 1024;
      bf16x8 kf0 = *(const bf16x8*)&Kfrag[kb];
      bf16x8 kf1 = *(const bf16x8*)&Kfrag[kb + 512];
      f32x4 s = __builtin_amdgcn_mfma_f32_16x16x32_bf16(kf0, qf0, z4, 0, 0, 0);
      s = __builtin_amdgcn_mfma_f32_16x16x32_bf16(kf1, qf1, s, 0, 0, 0);
      p[j][0] = __expf(s[0]); p[j][1] = __expf(s[1]);
      p[j][2] = __expf(s[2]); p[j][3] = __expf(s[3]);
      zh += (p[j][0] + p[j][1]) + (p[j][2] + p[j][3]);
    }
    zh += __shfl_xor(zh, 16); zh += __shfl_xor(zh, 32);
    __syncthreads();                 // prev h's zbuf reads complete
    if (quad == 0) zbuf[w][c] = zh;
    __syncthreads();                 // all wave partials visible
    float Z = ((zbuf[0][c] + zbuf[1][c]) + (zbuf[2][c] + zbuf[3][c]))
            + ((zbuf[4][c] + zbuf[5][c]) + (zbuf[6][c] + zbuf[7][c]));
    const float izq = 1.0f / Z;
    if (w == 0 && quad == 0) izbuf[h][c] = izq;
    const float cwz = conv_w[h] * izq;
#pragma unroll
    for (int j = 0; j < 8; j++) {
      g[j][0] += cwz * p[j][0]; g[j][1] += cwz * p[j][1];
      g[j][2] += cwz * p[j][2]; g[j][3] += cwz * p[j][3];
    }
  }

  // masks: bit(8r) = M_f (logit<=0), bit(8r+1) = M_r (logit>=0)
  unsigned int mmx[4], mmy[4];
#pragma unroll
  for (int t = 0; t < 4; t++) {
    unsigned int p0 = 0, p1 = 0;
#pragma unroll
    for (int r = 0; r < 4; r++) {
      p0 |= ((g[2 * t][r] <= 0.f ? 1u : 0u) | (g[2 * t][r] >= 0.f ? 2u : 0u)) << (8 * r);
      p1 |= ((g[2 * t + 1][r] <= 0.f ? 1u : 0u) | (g[2 * t + 1][r] >= 0.f ? 2u : 0u)) << (8 * r);
    }
    mmx[t] = p0; mmy[t] = p1;
  }
  __syncthreads();  // izbuf visible to all threads before phase 2

  frag_u ones;
  ones.u[0] = 0x3F803F80u; ones.u[1] = 0x3F803F80u;
  ones.u[2] = 0x3F803F80u; ones.u[3] = 0x3F803F80u;

  const int fr = w >> 2, dmslot = w & 3;
  const size_t tbase = (size_t)(b * 1024 + qt * 16 + c) * 512;
  unsigned short* dstsel = (fr == 0) ? Tfb : Trb;

  // ---------------- phase 2: PV with recompute ----------------
  for (int h = 0; h < 8; h++) {
    bf16x8 qf0 = *(const bf16x8*)&Qfrag[qbase + h * 1024];
    bf16x8 qf1 = *(const bf16x8*)&Qfrag[qbase + h * 1024 + 512];
    const float iz_h = izbuf[h][c];
    f32x4 accf[4], accr[4];
#pragma unroll
    for (int i = 0; i < 4; i++) { accf[i] = z4; accr[i] = z4; }
    f32x4 zf4 = z4, zr4 = z4;
#pragma unroll
    for (int t = 0; t < 4; t++) {
      const size_t kba = kb0 + (size_t)(2 * t) * 8192 + h * 1024;
      const size_t kbb = kba + 8192;
      bf16x8 ka0 = *(const bf16x8*)&Kfrag[kba];
      bf16x8 ka1 = *(const bf16x8*)&Kfrag[kba + 512];
      bf16x8 kb0f = *(const bf16x8*)&Kfrag[kbb];
      bf16x8 kb1f = *(const bf16x8*)&Kfrag[kbb + 512];
      f32x4 sa = __builtin_amdgcn_mfma_f32_16x16x32_bf16(ka0, qf0, z4, 0, 0, 0);
      sa = __builtin_amdgcn_mfma_f32_16x16x32_bf16(ka1, qf1, sa, 0, 0, 0);
      f32x4 sb = __builtin_amdgcn_mfma_f32_16x16x32_bf16(kb0f, qf0, z4, 0, 0, 0);
      sb = __builtin_amdgcn_mfma_f32_16x16x32_bf16(kb1f, qf1, sb, 0, 0, 0);
      float ea[4], eb[4];
#pragma unroll
      for (int r = 0; r < 4; r++) {
        ea[r] = __expf(__expf(sa[r]) * iz_h);
        eb[r] = __expf(__expf(sb[r]) * iz_h);
      }
      frag_u pF, pR;
      pF.u[0] = cvt_pk_bf16((mmx[t] & 0x1u)       ? ea[0] : 1.f, (mmx[t] & 0x100u)     ? ea[1] : 1.f);
      pF.u[1] = cvt_pk_bf16((mmx[t] & 0x10000u)   ? ea[2] : 1.f, (mmx[t] & 0x1000000u) ? ea[3] : 1.f);
      pF.u[2] = cvt_pk_bf16((mmy[t] & 0x1u)       ? eb[0] : 1.f, (mmy[t] & 0x100u)     ? eb[1] : 1.f);
      pF.u[3] = cvt_pk_bf16((mmy[t] & 0x10000u)   ? eb[2] : 1.f, (mmy[t] & 0x1000000u) ? eb[3] : 1.f);
      pR.u[0] = cvt_pk_bf16((mmx[t] & 0x2u)       ? ea[0] : 1.f, (mmx[t] & 0x200u)     ? ea[1] : 1.f);
      pR.u[1] = cvt_pk_bf16((mmx[t] & 0x20000u)   ? ea[2] : 1.f, (mmx[t] & 0x2000000u) ? ea[3] : 1.f);
      pR.u[2] = cvt_pk_bf16((mmy[t] & 0x2u)       ? eb[0] : 1.f, (mmy[t] & 0x200u)     ? eb[1] : 1.f);
      pR.u[3] = cvt_pk_bf16((mmy[t] & 0x20000u)   ? eb[2] : 1.f, (mmy[t] & 0x2000000u) ? eb[3] : 1.f);
      zf4 = __builtin_amdgcn_mfma_f32_16x16x32_bf16(ones.v, pF.v, zf4, 0, 0, 0);
      zr4 = __builtin_amdgcn_mfma_f32_16x16x32_bf16(ones.v, pR.v, zr4, 0, 0, 0);
      const size_t vbh = vb0 + (size_t)h * 65536 + (size_t)((w * 4 + t) * 4) * 512;
#pragma unroll
      for (int dm = 0; dm < 4; dm++) {
        bf16x8 vf = *(const bf16x8*)&Vfrag[vbh + (size_t)dm * 512];
        accf[dm] = __builtin_amdgcn_mfma_f32_16x16x32_bf16(vf, pF.v, accf[dm], 0, 0, 0);
        accr[dm] = __builtin_amdgcn_mfma_f32_16x16x32_bf16(vf, pR.v, accr[dm], 0, 0, 0);
      }
    }
    // cross-wave reduce: all waves write their partials, slot waves combine
    __syncthreads();   // prev h's slot reads complete
#pragma unroll
    for (int dm = 0; dm < 4; dm++) {
      *(f32x4*)&red[(((0 * 8 + w) * 4 + dm) * 64 + lane) * 4] = accf[dm];
      *(f32x4*)&red[(((1 * 8 + w) * 4 + dm) * 64 + lane) * 4] = accr[dm];
    }
    if (quad == 0) { zred[0][w][c] = zf4[0]; zred[1][w][c] = zr4[0]; }
    __syncthreads();
    {
      f32x4 o = z4;
#pragma unroll
      for (int w2 = 0; w2 < 8; w2++)
        o += *(const f32x4*)&red[(((fr * 8 + w2) * 4 + dmslot) * 64 + lane) * 4];
      float Zq = 0.f;
#pragma unroll
      for (int w2 = 0; w2 < 8; w2++) Zq += zred[fr][w2][c];
      const float iz = 1.0f / Zq;
      uint2 u;
      u.x = cvt_pk_bf16(o[0] * iz, o[1] * iz);
      u.y = cvt_pk_bf16(o[2] * iz, o[3] * iz);
      *(uint2*)&dstsel[tbase + h * 64 + dmslot * 16 + quad * 4] = u;
    }
  }
}

// ---------------------------------------------------------------------------
// Kernel 4: final — LDS-staged fused 4-GEMM + gate combine, 64x64 tile
// (R13 exact: single-buffered; R14's dbuf variant regressed +4us).
// ---------------------------------------------------------------------------
__global__ __launch_bounds__(256, 2) void final_kernel(
    const unsigned short* __restrict__ Tfb, const unsigned short* __restrict__ Trb,
    const unsigned short* __restrict__ wfh, const unsigned short* __restrict__ wfg,
    const unsigned short* __restrict__ wrh, const unsigned short* __restrict__ wrg,
    const float* __restrict__ bfh, const float* __restrict__ bfg,
    const float* __restrict__ brh, const float* __restrict__ brg,
    float* __restrict__ out) {
  __shared__ unsigned short Atf[64 * 64];
  __shared__ unsigned short Atr[64 * 64];
  __shared__ unsigned short Bfh[64 * 64];
  __shared__ unsigned short Bfg[64 * 64];
  __shared__ unsigned short Brh[64 * 64];
  __shared__ unsigned short Brg[64 * 64];
  const int m0 = blockIdx.y * 64, n0 = blockIdx.x * 64;
  const int tid = threadIdx.x, w = tid >> 6, lane = tid & 63;
  const int c = lane & 15, quad = lane >> 4;
  const int wm = w & 1, wn = w >> 1;
  const int rsel = lane >> 3, csel = lane & 7;
  const int sc = csel ^ rsel;
  // every tile: wave stages 16 rows (2 gload16 per buffer).
  const char* Agf = (const char*)Tfb + (size_t)(m0 + w * 16 + rsel) * 1024 + sc * 16;
  const char* Agr = (const char*)Trb + (size_t)(m0 + w * 16 + rsel) * 1024 + sc * 16;
  const char* Bg0 = (const char*)wfh + (size_t)(n0 + w * 16 + rsel) * 1024 + sc * 16;
  const char* Bg1 = (const char*)wfg + (size_t)(n0 + w * 16 + rsel) * 1024 + sc * 16;
  const char* Bg2 = (const char*)wrh + (size_t)(n0 + w * 16 + rsel) * 1024 + sc * 16;
  const char* Bg3 = (const char*)wrg + (size_t)(n0 + w * 16 + rsel) * 1024 + sc * 16;
  unsigned short* lAf = &Atf[w * 1024];
  unsigned short* lAr = &Atr[w * 1024];
  unsigned short* l0 = &Bfh[w * 1024];
  unsigned short* l1 = &Bfg[w * 1024];
  unsigned short* l2 = &Brh[w * 1024];
  unsigned short* l3 = &Brg[w * 1024];

  f32x4 acc[4][2][2];  // [mat][m][nt]
  f32x4 z4 = {0.f, 0.f, 0.f, 0.f};
#pragma unroll
  for (int o = 0; o < 4; o++)
#pragma unroll
    for (int m = 0; m < 2; m++)
#pragma unroll
      for (int j = 0; j < 2; j++) acc[o][m][j] = z4;

  for (int ks = 0; ks < 8; ks++) {
    if (ks) __syncthreads();
    const int kb = ks * 128;
    gload16(Agf + kb, lAf);  gload16(Agf + kb + 8192, lAf + 512);
    gload16(Agr + kb, lAr);  gload16(Agr + kb + 8192, lAr + 512);
    gload16(Bg0 + kb, l0);   gload16(Bg0 + kb + 8192, l0 + 512);
    gload16(Bg1 + kb, l1);   gload16(Bg1 + kb + 8192, l1 + 512);
    gload16(Bg2 + kb, l2);   gload16(Bg2 + kb + 8192, l2 + 512);
    gload16(Bg3 + kb, l3);   gload16(Bg3 + kb + 8192, l3 + 512);
    __syncthreads();
#pragma unroll
    for (int ch = 0; ch < 2; ch++) {
      const int cq = ch * 4 + quad;
      bf16x8 af0 = lds_frag(Atf, wm * 32 + c, cq);
      bf16x8 af1 = lds_frag(Atf, wm * 32 + 16 + c, cq);
      bf16x8 ar0 = lds_frag(Atr, wm * 32 + c, cq);
      bf16x8 ar1 = lds_frag(Atr, wm * 32 + 16 + c, cq);
#pragma unroll
      for (int nt = 0; nt < 2; nt++) {
        const int rb = wn * 32 + nt * 16 + c;
        bf16x8 f0 = lds_frag(Bfh, rb, cq);
        bf16x8 f1 = lds_frag(Bfg, rb, cq);
        bf16x8 f2 = lds_frag(Brh, rb, cq);
        bf16x8 f3 = lds_frag(Brg, rb, cq);
        acc[0][0][nt] = __builtin_amdgcn_mfma_f32_16x16x32_bf16(af0, f0, acc[0][0][nt], 0, 0, 0);
        acc[0][1][nt] = __builtin_amdgcn_mfma_f32_16x16x32_bf16(af1, f0, acc[0][1][nt], 0, 0, 0);
        acc[1][0][nt] = __builtin_amdgcn_mfma_f32_16x16x32_bf16(af0, f1, acc[1][0][nt], 0, 0, 0);
        acc[1][1][nt] = __builtin_amdgcn_mfma_f32_16x16x32_bf16(af1, f1, acc[1][1][nt], 0, 0, 0);
        acc[2][0][nt] = __builtin_amdgcn_mfma_f32_16x16x32_bf16(ar0, f2, acc[2][0][nt], 0, 0, 0);
        acc[2][1][nt] = __builtin_amdgcn_mfma_f32_16x16x32_bf16(ar1, f2, acc[2][1][nt], 0, 0, 0);
        acc[3][0][nt] = __builtin_amdgcn_mfma_f32_16x16x32_bf16(ar0, f3, acc[3][0][nt], 0, 0, 0);
        acc[3][1][nt] = __builtin_amdgcn_mfma_f32_16x16x32_bf16(ar1, f3, acc[3][1][nt], 0, 0, 0);
      }
    }
  }

#pragma unroll
  for (int nt = 0; nt < 2; nt++) {
    int n = n0 + wn * 32 + nt * 16 + c;
    float b0 = bfh[n], b1 = bfg[n], b2 = brh[n], b3 = brg[n];
#pragma unroll
    for (int m = 0; m < 2; m++) {
      int t0 = m0 + wm * 32 + m * 16 + quad * 4;
#pragma unroll
      for (int r = 0; r < 4; r++) {
        int t = t0 + r;
        float Ff = acc[0][m][nt][r] + b0;
        float Gf = 1.0f / (1.0f + __expf(-(acc[1][m][nt][r] + b1)));
        float Fr = acc[2][m][nt][r] + b2;
        float Gr = 1.0f / (1.0f + __expf(-(acc[3][m][nt][r] + b3)));
        float ef = __expf(Gf), er = __expf(Gr);
        out[(size_t)t * 512 + n] = (Ff * ef + Fr * er) / (ef + er);
      }
    }
  }
}

// ---------------------------------------------------------------------------
// Launch. Workspace (bytes):
//   0: xb 4MB | 4: Qfrag 4MB | 8: Kfrag 4MB | 12: Vfrag 4MB
//   16: Tfb 4MB | 20: Trb 4MB | 24: wt 3.5MB
// ---------------------------------------------------------------------------
extern "C" void kernel_launch(void* const* d_in, const int* in_sizes, int n_in,
                              void* d_out, int out_size, void* d_ws, size_t ws_size,
                              hipStream_t stream) {
  const float* x   = (const float*)d_in[0];
  const float* Wq  = (const float*)d_in[1];
  const float* bq  = (const float*)d_in[2];
  const float* Wk  = (const float*)d_in[3];
  const float* bk  = (const float*)d_in[4];
  const float* Wv  = (const float*)d_in[5];
  const float* bv  = (const float*)d_in[6];
  const float* cw  = (const float*)d_in[7];
  const float* cb  = (const float*)d_in[8];
  const float* Wfh = (const float*)d_in[9];
  const float* bfh = (const float*)d_in[10];
  const float* Wfg = (const float*)d_in[11];
  const float* bfg = (const float*)d_in[12];
  const float* Wrh = (const float*)d_in[13];
  const float* brh = (const float*)d_in[14];
  const float* Wrg = (const float*)d_in[15];
  const float* brg = (const float*)d_in[16];

  char* ws = (char*)d_ws;
  const size_t MB = 1024 * 1024;
  unsigned short* xb    = (unsigned short*)(ws + 0 * MB);
  unsigned short* Qfrag = (unsigned short*)(ws + 4 * MB);
  unsigned short* Kfrag = (unsigned short*)(ws + 8 * MB);
  unsigned short* Vfrag = (unsigned short*)(ws + 12 * MB);
  unsigned short* Tfb   = (unsigned short*)(ws + 16 * MB);
  unsigned short* Trb   = (unsigned short*)(ws + 20 * MB);
  unsigned short* wt    = (unsigned short*)(ws + 24 * MB);
  const size_t WSZ = 512 * 512;

  prep_kernel<<<704, 256, 0, stream>>>(x, Wq, Wk, Wv, Wfh, Wfg, Wrh, Wrg, xb, wt);
  qkv_kernel<<<dim3(8, 64), 256, 0, stream>>>(xb, wt + 0 * WSZ, wt + 1 * WSZ, wt + 2 * WSZ,
                                              bq, bk, bv, Qfrag, Kfrag, Vfrag);
  attn_kernel<<<dim3(4, 64), 512, 0, stream>>>(Qfrag, Kfrag, Vfrag, cw, cb, Tfb, Trb);
  final_kernel<<<dim3(8, 64), 256, 0, stream>>>(Tfb, Trb, wt + 3 * WSZ, wt + 4 * WSZ,
                                                wt + 5 * WSZ, wt + 6 * WSZ,
                                                bfh, bfg, brh, brg, (float*)d_out);
}

// Round 17
// 171.088 us; speedup vs baseline: 1.3123x; 1.0198x over previous
//
#include <hip/hip_runtime.h>
#include <hip/hip_bf16.h>
#include <stdint.h>

typedef short bf16x8 __attribute__((ext_vector_type(8)));
typedef float f32x4 __attribute__((ext_vector_type(4)));

__device__ __forceinline__ unsigned short f2bf(float f) {
  union { float f; unsigned int u; } v;
  v.f = f;
  unsigned int u = v.u;
  u = (u + 0x7fffu + ((u >> 16) & 1u)) >> 16;  // RNE
  return (unsigned short)u;
}

// HW packed f32->bf16 RNE conversion (bit-identical to f2bf).
__device__ __forceinline__ unsigned int cvt_pk_bf16(float lo, float hi) {
  unsigned int r;
  asm("v_cvt_pk_bf16_f32 %0, %1, %2" : "=v"(r) : "v"(lo), "v"(hi));
  return r;
}

typedef union { bf16x8 v; unsigned int u[4]; } frag_u;

// global->LDS async copy, 16B per lane.
__device__ __forceinline__ void gload16(const void* g, void* lds) {
  __builtin_amdgcn_global_load_lds(
      (const __attribute__((address_space(1))) unsigned int*)(unsigned long long)g,
      (__attribute__((address_space(3))) unsigned int*)(unsigned long long)(unsigned)(unsigned long long)lds,
      16, 0, 0);
}

__device__ __forceinline__ bf16x8 lds_frag(const unsigned short* t, int row, int ch4q) {
  return *(const bf16x8*)(t + row * 64 + ((ch4q ^ (row & 7)) << 3));
}

// Fragment layouts (element = short unless noted):
//  Qfrag/Kfrag[b][t16][h][sub][lane]: ((b*64+t16)*8192) + h*1024 + sub*512 + lane*8
//  Vfrag PAIRED [b][h][ktp][dm][lane][8]: (b*8+h)*65536 + (ktp*4+dm)*512 + lane*8

// ---------------------------------------------------------------------------
// Kernel 1: prep — x -> bf16 (blocks 0..255 first), weights -> transposed bf16.
// ---------------------------------------------------------------------------
__global__ __launch_bounds__(256) void prep_kernel(
    const float* __restrict__ x,
    const float* __restrict__ Wq, const float* __restrict__ Wk, const float* __restrict__ Wv,
    const float* __restrict__ Wfh, const float* __restrict__ Wfg,
    const float* __restrict__ Wrh, const float* __restrict__ Wrg,
    unsigned short* __restrict__ xb, unsigned short* __restrict__ wt) {
  int bid = blockIdx.x;
  int tid = threadIdx.x;
  if (bid < 256) {
    const float4* xi = (const float4*)x;
#pragma unroll
    for (int rep = 0; rep < 8; rep++) {
      int i = bid * 256 + tid + rep * 65536;
      float4 v = xi[i];
      uint2 u;
      u.x = cvt_pk_bf16(v.x, v.y);
      u.y = cvt_pk_bf16(v.z, v.w);
      *(uint2*)&xb[(size_t)i * 4] = u;
    }
  } else {
    __shared__ float tile[64][65];
    int t = bid - 256;
    int mat = t >> 6;
    t &= 63;
    int tr = (t >> 3) * 64, tc = (t & 7) * 64;
    const float* W = (mat == 0) ? Wq : (mat == 1) ? Wk : (mat == 2) ? Wv
                   : (mat == 3) ? Wfh : (mat == 4) ? Wfg : (mat == 5) ? Wrh : Wrg;
    unsigned short* Wt = wt + (size_t)mat * 512 * 512;
    for (int rep = 0; rep < 16; rep++) {
      int idx = rep * 256 + tid;
      int r = idx >> 6, c = idx & 63;
      tile[r][c] = W[(tr + r) * 512 + tc + c];
    }
    __syncthreads();
    for (int rep = 0; rep < 16; rep++) {
      int idx = rep * 256 + tid;
      int r = idx >> 6, c = idx & 63;
      Wt[(tc + r) * 512 + tr + c] = f2bf(tile[c][r]);
    }
  }
}

// ---------------------------------------------------------------------------
// Kernel 2: QKV projection — DOUBLE-BUFFERED staging (R13 exact).
// ---------------------------------------------------------------------------
__global__ __launch_bounds__(256, 2) void qkv_kernel(
    const unsigned short* __restrict__ xb,
    const unsigned short* __restrict__ wtq, const unsigned short* __restrict__ wtk,
    const unsigned short* __restrict__ wtv,
    const float* __restrict__ bq, const float* __restrict__ bk, const float* __restrict__ bv,
    unsigned short* __restrict__ Qfrag, unsigned short* __restrict__ Kfrag,
    unsigned short* __restrict__ Vfrag) {
  __shared__ __attribute__((aligned(16))) unsigned short smem[32768];  // 64 KB
  // buffer layout (shorts, per 16384-short buffer): As=+0 Bq=+4096 Bk=+8192 Bv=+12288
  unsigned short* st0 = smem;                // [64*72] each, epilogue only
  unsigned short* st1 = smem + 4608;
  unsigned short* st2 = smem + 9216;
  const int m0 = blockIdx.y * 64, n0 = blockIdx.x * 64;
  const int tid = threadIdx.x, w = tid >> 6, lane = tid & 63;
  const int c = lane & 15, quad = lane >> 4;
  const int wm = w & 1, wn = w >> 1;
  const int rsel = lane >> 3, csel = lane & 7;
  const int sc = csel ^ rsel;
  const char* Ag  = (const char*)xb  + (size_t)(m0 + w * 16 + rsel) * 1024 + sc * 16;
  const char* Bgq = (const char*)wtq + (size_t)(n0 + w * 16 + rsel) * 1024 + sc * 16;
  const char* Bgk = (const char*)wtk + (size_t)(n0 + w * 16 + rsel) * 1024 + sc * 16;
  const char* Bgv = (const char*)wtv + (size_t)(n0 + w * 16 + rsel) * 1024 + sc * 16;
  const int woff = w * 1024;

  f32x4 acc[3][2][2];
  f32x4 z4 = {0.f, 0.f, 0.f, 0.f};
#pragma unroll
  for (int o = 0; o < 3; o++)
#pragma unroll
    for (int i = 0; i < 2; i++)
#pragma unroll
      for (int j = 0; j < 2; j++) acc[o][i][j] = z4;

  // prologue: stage ks=0 into buf0
  {
    unsigned short* base = smem;
    gload16(Ag, base + woff);              gload16(Ag + 8192, base + woff + 512);
    gload16(Bgq, base + 4096 + woff);      gload16(Bgq + 8192, base + 4096 + woff + 512);
    gload16(Bgk, base + 8192 + woff);      gload16(Bgk + 8192, base + 8192 + woff + 512);
    gload16(Bgv, base + 12288 + woff);     gload16(Bgv + 8192, base + 12288 + woff + 512);
  }
  __syncthreads();

  for (int ks = 0; ks < 8; ks++) {
    unsigned short* cur = smem + (ks & 1) * 16384;
    if (ks < 7) {
      unsigned short* nxt = smem + ((ks + 1) & 1) * 16384;
      const int kb = (ks + 1) * 128;
      gload16(Ag + kb, nxt + woff);          gload16(Ag + kb + 8192, nxt + woff + 512);
      gload16(Bgq + kb, nxt + 4096 + woff);  gload16(Bgq + kb + 8192, nxt + 4096 + woff + 512);
      gload16(Bgk + kb, nxt + 8192 + woff);  gload16(Bgk + kb + 8192, nxt + 8192 + woff + 512);
      gload16(Bgv + kb, nxt + 12288 + woff); gload16(Bgv + kb + 8192, nxt + 12288 + woff + 512);
    }
#pragma unroll
    for (int ch = 0; ch < 2; ch++) {
      const int cq = ch * 4 + quad;
      bf16x8 a0 = lds_frag(cur, wm * 32 + c, cq);
      bf16x8 a1 = lds_frag(cur, wm * 32 + 16 + c, cq);
#pragma unroll
      for (int nt = 0; nt < 2; nt++) {
        const int rb = wn * 32 + nt * 16 + c;
        bf16x8 fq = lds_frag(cur + 4096, rb, cq);
        bf16x8 fk = lds_frag(cur + 8192, rb, cq);
        bf16x8 fv = lds_frag(cur + 12288, rb, cq);
        acc[0][0][nt] = __builtin_amdgcn_mfma_f32_16x16x32_bf16(a0, fq, acc[0][0][nt], 0, 0, 0);
        acc[0][1][nt] = __builtin_amdgcn_mfma_f32_16x16x32_bf16(a1, fq, acc[0][1][nt], 0, 0, 0);
        acc[1][0][nt] = __builtin_amdgcn_mfma_f32_16x16x32_bf16(a0, fk, acc[1][0][nt], 0, 0, 0);
        acc[1][1][nt] = __builtin_amdgcn_mfma_f32_16x16x32_bf16(a1, fk, acc[1][1][nt], 0, 0, 0);
        acc[2][0][nt] = __builtin_amdgcn_mfma_f32_16x16x32_bf16(a0, fv, acc[2][0][nt], 0, 0, 0);
        acc[2][1][nt] = __builtin_amdgcn_mfma_f32_16x16x32_bf16(a1, fv, acc[2][1][nt], 0, 0, 0);
      }
    }
    __syncthreads();  // drains next-tile DMA + guards cur reuse
  }

  // stage: st0=Q[t][d], st1=K[t][d], st2=V[d][t]  (st unions over buf0, dead)
#pragma unroll
  for (int ms = 0; ms < 2; ms++)
#pragma unroll
    for (int nt = 0; nt < 2; nt++) {
      int n_l = wn * 32 + nt * 16 + c;
      int n = n0 + n_l;
      float biasq = bq[n], biask = bk[n], biasv = bv[n];
#pragma unroll
      for (int r = 0; r < 4; r++) {
        int m_l = wm * 32 + ms * 16 + quad * 4 + r;
        st0[m_l * 72 + n_l] = f2bf((acc[0][ms][nt][r] + biasq) * 0.125f);
        st1[m_l * 72 + n_l] = f2bf(acc[1][ms][nt][r] + biask);
        st2[n_l * 72 + m_l] = f2bf(acc[2][ms][nt][r] + biasv);
      }
    }
  __syncthreads();

  {
    const int h = n0 >> 6;
    const int bb = m0 >> 10, t0b = (m0 & 1023) >> 4;
#pragma unroll
    for (int sub = 0; sub < 2; sub++) {
      uint4 vq = *(uint4*)&st0[(w * 16 + c) * 72 + sub * 32 + quad * 8];
      uint4 vk = *(uint4*)&st1[(w * 16 + c) * 72 + sub * 32 + quad * 8];
      size_t base = (size_t)((bb * 64 + t0b + w) * 8192) + h * 1024 + sub * 512 + lane * 8;
      *(uint4*)&Qfrag[base] = vq;
      *(uint4*)&Kfrag[base] = vk;
    }
    // pair-packed V fragments: kt = t0b + w; half = kt&1 selects shorts 0..3/4..7
    const int ktq = t0b + w;
    const int ktp = ktq >> 1, half = ktq & 1;
#pragma unroll
    for (int dm = 0; dm < 4; dm++) {
      uint2 vv = *(uint2*)&st2[(dm * 16 + c) * 72 + w * 16 + quad * 4];
      size_t base = (size_t)(bb * 8 + h) * 65536 + (size_t)(ktp * 4 + dm) * 512
                  + lane * 8 + half * 4;
      *(uint2*)&Vfrag[base] = vv;
    }
  }
}

// ---------------------------------------------------------------------------
// Kernel 3: attn — FUSED zgate+pv. EXACT R9/R13 body, FROZEN.
// grid (4 b, 64 qt16), 512 thr = 8 waves; wave w owns kt = 8w..8w+7.
// launch_bounds (512,2): measured VGPR=64, 56.3-56.8us, zero spill.
// DO NOT PERTURB: R6 (1024thr) spilled; R7 (h-pair+wpe) 67us; R8 (P-cache)
// spilled; R11 (wpe alone) 67us @ VGPR 88; R12 (barrier-halving) 67us @
// VGPR 88; R15 (fused final epilogue) 130us @ VGPR 128 + 327K bank
// conflicts. Every deviation from this source shifts codegen off the
// 64-VGPR schedule and costs 11-70us.
// ---------------------------------------------------------------------------
__global__ __launch_bounds__(512, 2) void attn_kernel(
    const unsigned short* __restrict__ Qfrag, const unsigned short* __restrict__ Kfrag,
    const unsigned short* __restrict__ Vfrag,
    const float* __restrict__ conv_w, const float* __restrict__ conv_b,
    unsigned short* __restrict__ Tfb, unsigned short* __restrict__ Trb) {
  const int b = blockIdx.x, qt = blockIdx.y;
  const int tid = threadIdx.x, w = tid >> 6, lane = tid & 63;
  const int c = lane & 15, quad = lane >> 4;
  __shared__ float zbuf[8][16];
  __shared__ float izbuf[8][16];
  __shared__ __attribute__((aligned(16))) float red[2 * 8 * 4 * 64 * 4];  // 64 KB
  __shared__ float zred[2][8][16];

  f32x4 z4 = {0.f, 0.f, 0.f, 0.f};
  const float cb = conv_b[0];
  const size_t qbase = (size_t)((b * 64 + qt) * 8192) + lane * 8;
  const size_t kb0 = (size_t)((b * 64 + w * 8) * 8192) + lane * 8;
  const size_t vb0 = (size_t)(b * 8) * 65536 + lane * 8;  // + h*65536

  f32x4 g[8];
#pragma unroll
  for (int j = 0; j < 8; j++) g[j] = {cb, cb, cb, cb};

  // ---------------- phase 1: Z + gate logits ----------------
  for (int h = 0; h < 8; h++) {
    bf16x8 qf0 = *(const bf16x8*)&Qfrag[qbase + h * 1024];
    bf16x8 qf1 = *(const bf16x8*)&Qfrag[qbase + h * 1024 + 512];
    f32x4 p[8];
    float zh = 0.f;
#pragma unroll
    for (int j = 0; j < 8; j++) {
      const size_t kb = kb0 + (size_t)j * 8192 + h * 1024;
      bf16x8 kf0 = *(const bf16x8*)&Kfrag[kb];
      bf16x8 kf1 = *(const bf16x8*)&Kfrag[kb + 512];
      f32x4 s = __builtin_amdgcn_mfma_f32_16x16x32_bf16(kf0, qf0, z4, 0, 0, 0);
      s = __builtin_amdgcn_mfma_f32_16x16x32_bf16(kf1, qf1, s, 0, 0, 0);
      p[j][0] = __expf(s[0]); p[j][1] = __expf(s[1]);
      p[j][2] = __expf(s[2]); p[j][3] = __expf(s[3]);
      zh += (p[j][0] + p[j][1]) + (p[j][2] + p[j][3]);
    }
    zh += __shfl_xor(zh, 16); zh += __shfl_xor(zh, 32);
    __syncthreads();                 // prev h's zbuf reads complete
    if (quad == 0) zbuf[w][c] = zh;
    __syncthreads();                 // all wave partials visible
    float Z = ((zbuf[0][c] + zbuf[1][c]) + (zbuf[2][c] + zbuf[3][c]))
            + ((zbuf[4][c] + zbuf[5][c]) + (zbuf[6][c] + zbuf[7][c]));
    const float izq = 1.0f / Z;
    if (w == 0 && quad == 0) izbuf[h][c] = izq;
    const float cwz = conv_w[h] * izq;
#pragma unroll
    for (int j = 0; j < 8; j++) {
      g[j][0] += cwz * p[j][0]; g[j][1] += cwz * p[j][1];
      g[j][2] += cwz * p[j][2]; g[j][3] += cwz * p[j][3];
    }
  }

  // masks: bit(8r) = M_f (logit<=0), bit(8r+1) = M_r (logit>=0)
  unsigned int mmx[4], mmy[4];
#pragma unroll
  for (int t = 0; t < 4; t++) {
    unsigned int p0 = 0, p1 = 0;
#pragma unroll
    for (int r = 0; r < 4; r++) {
      p0 |= ((g[2 * t][r] <= 0.f ? 1u : 0u) | (g[2 * t][r] >= 0.f ? 2u : 0u)) << (8 * r);
      p1 |= ((g[2 * t + 1][r] <= 0.f ? 1u : 0u) | (g[2 * t + 1][r] >= 0.f ? 2u : 0u)) << (8 * r);
    }
    mmx[t] = p0; mmy[t] = p1;
  }
  __syncthreads();  // izbuf visible to all threads before phase 2

  frag_u ones;
  ones.u[0] = 0x3F803F80u; ones.u[1] = 0x3F803F80u;
  ones.u[2] = 0x3F803F80u; ones.u[3] = 0x3F803F80u;

  const int fr = w >> 2, dmslot = w & 3;
  const size_t tbase = (size_t)(b * 1024 + qt * 16 + c) * 512;
  unsigned short* dstsel = (fr == 0) ? Tfb : Trb;

  // ---------------- phase 2: PV with recompute ----------------
  for (int h = 0; h < 8; h++) {
    bf16x8 qf0 = *(const bf16x8*)&Qfrag[qbase + h * 1024];
    bf16x8 qf1 = *(const bf16x8*)&Qfrag[qbase + h * 1024 + 512];
    const float iz_h = izbuf[h][c];
    f32x4 accf[4], accr[4];
#pragma unroll
    for (int i = 0; i < 4; i++) { accf[i] = z4; accr[i] = z4; }
    f32x4 zf4 = z4, zr4 = z4;
#pragma unroll
    for (int t = 0; t < 4; t++) {
      const size_t kba = kb0 + (size_t)(2 * t) * 8192 + h * 1024;
      const size_t kbb = kba + 8192;
      bf16x8 ka0 = *(const bf16x8*)&Kfrag[kba];
      bf16x8 ka1 = *(const bf16x8*)&Kfrag[kba + 512];
      bf16x8 kb0f = *(const bf16x8*)&Kfrag[kbb];
      bf16x8 kb1f = *(const bf16x8*)&Kfrag[kbb + 512];
      f32x4 sa = __builtin_amdgcn_mfma_f32_16x16x32_bf16(ka0, qf0, z4, 0, 0, 0);
      sa = __builtin_amdgcn_mfma_f32_16x16x32_bf16(ka1, qf1, sa, 0, 0, 0);
      f32x4 sb = __builtin_amdgcn_mfma_f32_16x16x32_bf16(kb0f, qf0, z4, 0, 0, 0);
      sb = __builtin_amdgcn_mfma_f32_16x16x32_bf16(kb1f, qf1, sb, 0, 0, 0);
      float ea[4], eb[4];
#pragma unroll
      for (int r = 0; r < 4; r++) {
        ea[r] = __expf(__expf(sa[r]) * iz_h);
        eb[r] = __expf(__expf(sb[r]) * iz_h);
      }
      frag_u pF, pR;
      pF.u[0] = cvt_pk_bf16((mmx[t] & 0x1u)       ? ea[0] : 1.f, (mmx[t] & 0x100u)     ? ea[1] : 1.f);
      pF.u[1] = cvt_pk_bf16((mmx[t] & 0x10000u)   ? ea[2] : 1.f, (mmx[t] & 0x1000000u) ? ea[3] : 1.f);
      pF.u[2] = cvt_pk_bf16((mmy[t] & 0x1u)       ? eb[0] : 1.f, (mmy[t] & 0x100u)     ? eb[1] : 1.f);
      pF.u[3] = cvt_pk_bf16((mmy[t] & 0x10000u)   ? eb[2] : 1.f, (mmy[t] & 0x1000000u) ? eb[3] : 1.f);
      pR.u[0] = cvt_pk_bf16((mmx[t] & 0x2u)       ? ea[0] : 1.f, (mmx[t] & 0x200u)     ? ea[1] : 1.f);
      pR.u[1] = cvt_pk_bf16((mmx[t] & 0x20000u)   ? ea[2] : 1.f, (mmx[t] & 0x2000000u) ? ea[3] : 1.f);
      pR.u[2] = cvt_pk_bf16((mmy[t] & 0x2u)       ? eb[0] : 1.f, (mmy[t] & 0x200u)     ? eb[1] : 1.f);
      pR.u[3] = cvt_pk_bf16((mmy[t] & 0x20000u)   ? eb[2] : 1.f, (mmy[t] & 0x2000000u) ? eb[3] : 1.f);
      zf4 = __builtin_amdgcn_mfma_f32_16x16x32_bf16(ones.v, pF.v, zf4, 0, 0, 0);
      zr4 = __builtin_amdgcn_mfma_f32_16x16x32_bf16(ones.v, pR.v, zr4, 0, 0, 0);
      const size_t vbh = vb0 + (size_t)h * 65536 + (size_t)((w * 4 + t) * 4) * 512;
#pragma unroll
      for (int dm = 0; dm < 4; dm++) {
        bf16x8 vf = *(const bf16x8*)&Vfrag[vbh + (size_t)dm * 512];
        accf[dm] = __builtin_amdgcn_mfma_f32_16x16x32_bf16(vf, pF.v, accf[dm], 0, 0, 0);
        accr[dm] = __builtin_amdgcn_mfma_f32_16x16x32_bf16(vf, pR.v, accr[dm], 0, 0, 0);
      }
    }
    // cross-wave reduce: all waves write their partials, slot waves combine
    __syncthreads();   // prev h's slot reads complete
#pragma unroll
    for (int dm = 0; dm < 4; dm++) {
      *(f32x4*)&red[(((0 * 8 + w) * 4 + dm) * 64 + lane) * 4] = accf[dm];
      *(f32x4*)&red[(((1 * 8 + w) * 4 + dm) * 64 + lane) * 4] = accr[dm];
    }
    if (quad == 0) { zred[0][w][c] = zf4[0]; zred[1][w][c] = zr4[0]; }
    __syncthreads();
    {
      f32x4 o = z4;
#pragma unroll
      for (int w2 = 0; w2 < 8; w2++)
        o += *(const f32x4*)&red[(((fr * 8 + w2) * 4 + dmslot) * 64 + lane) * 4];
      float Zq = 0.f;
#pragma unroll
      for (int w2 = 0; w2 < 8; w2++) Zq += zred[fr][w2][c];
      const float iz = 1.0f / Zq;
      uint2 u;
      u.x = cvt_pk_bf16(o[0] * iz, o[1] * iz);
      u.y = cvt_pk_bf16(o[2] * iz, o[3] * iz);
      *(uint2*)&dstsel[tbase + h * 64 + dmslot * 16 + quad * 4] = u;
    }
  }
}

// ---------------------------------------------------------------------------
// Kernel 4: final — fused 4-GEMM + gate combine, 64m x 32n TILES.
// grid (16 nb, 64 mt64) = 1024 blocks -> 4 blocks/CU (LDS 32 KB,
// launch_bounds(256,4)) = 16 waves/CU: 2x the TLP of the 2/CU variants.
// Diagnosis by elimination: 64x64 tile (R11) neutral, dbuf (R14) regressed
// -> final is block-level latency-bound; TLP is the untested lever.
// Waves 2m x 2n; per wave 32m x 16n per mat; 8 LDS reads : 16 MFMA per step.
// LDS layout (shorts): Atf=+0(4096) Atr=+4096 B0..B3=+8192,+10240,+12288,+14336.
// ---------------------------------------------------------------------------
__global__ __launch_bounds__(256, 4) void final_kernel(
    const unsigned short* __restrict__ Tfb, const unsigned short* __restrict__ Trb,
    const unsigned short* __restrict__ wfh, const unsigned short* __restrict__ wfg,
    const unsigned short* __restrict__ wrh, const unsigned short* __restrict__ wrg,
    const float* __restrict__ bfh, const float* __restrict__ bfg,
    const float* __restrict__ brh, const float* __restrict__ brg,
    float* __restrict__ out) {
  __shared__ __attribute__((aligned(16))) unsigned short smem[16384];  // 32 KB
  const int m0 = blockIdx.y * 64, n0 = blockIdx.x * 32;
  const int tid = threadIdx.x, w = tid >> 6, lane = tid & 63;
  const int c = lane & 15, quad = lane >> 4;
  const int wm = w & 1, wn = w >> 1;
  const int rsel = lane >> 3, csel = lane & 7;
  const int sc = csel ^ rsel;
  // A tiles (64 rows): wave stages 16 rows each (2 gload16 per mat).
  // B tiles (32 rows): wave stages 8 rows each (1 gload16 per mat).
  const char* Agf = (const char*)Tfb + (size_t)(m0 + w * 16 + rsel) * 1024 + sc * 16;
  const char* Agr = (const char*)Trb + (size_t)(m0 + w * 16 + rsel) * 1024 + sc * 16;
  const char* Bg0 = (const char*)wfh + (size_t)(n0 + w * 8 + rsel) * 1024 + sc * 16;
  const char* Bg1 = (const char*)wfg + (size_t)(n0 + w * 8 + rsel) * 1024 + sc * 16;
  const char* Bg2 = (const char*)wrh + (size_t)(n0 + w * 8 + rsel) * 1024 + sc * 16;
  const char* Bg3 = (const char*)wrg + (size_t)(n0 + w * 8 + rsel) * 1024 + sc * 16;
  unsigned short* lAf = smem + w * 1024;            // 16 rows
  unsigned short* lAr = smem + 4096 + w * 1024;
  unsigned short* l0 = smem + 8192 + w * 512;       // 8 rows
  unsigned short* l1 = smem + 10240 + w * 512;
  unsigned short* l2 = smem + 12288 + w * 512;
  unsigned short* l3 = smem + 14336 + w * 512;

  f32x4 acc[4][2];  // [mat][m2]; single n-tile per wave
  f32x4 z4 = {0.f, 0.f, 0.f, 0.f};
#pragma unroll
  for (int o = 0; o < 4; o++)
#pragma unroll
    for (int m = 0; m < 2; m++) acc[o][m] = z4;

  for (int ks = 0; ks < 8; ks++) {
    if (ks) __syncthreads();
    const int kb = ks * 128;
    gload16(Agf + kb, lAf);  gload16(Agf + kb + 8192, lAf + 512);
    gload16(Agr + kb, lAr);  gload16(Agr + kb + 8192, lAr + 512);
    gload16(Bg0 + kb, l0);
    gload16(Bg1 + kb, l1);
    gload16(Bg2 + kb, l2);
    gload16(Bg3 + kb, l3);
    __syncthreads();
#pragma unroll
    for (int ch = 0; ch < 2; ch++) {
      const int cq = ch * 4 + quad;
      bf16x8 af0 = lds_frag(smem, wm * 32 + c, cq);
      bf16x8 af1 = lds_frag(smem, wm * 32 + 16 + c, cq);
      bf16x8 ar0 = lds_frag(smem + 4096, wm * 32 + c, cq);
      bf16x8 ar1 = lds_frag(smem + 4096, wm * 32 + 16 + c, cq);
      const int rb = wn * 16 + c;
      bf16x8 f0 = lds_frag(smem + 8192, rb, cq);
      bf16x8 f1 = lds_frag(smem + 10240, rb, cq);
      bf16x8 f2 = lds_frag(smem + 12288, rb, cq);
      bf16x8 f3 = lds_frag(smem + 14336, rb, cq);
      acc[0][0] = __builtin_amdgcn_mfma_f32_16x16x32_bf16(af0, f0, acc[0][0], 0, 0, 0);
      acc[0][1] = __builtin_amdgcn_mfma_f32_16x16x32_bf16(af1, f0, acc[0][1], 0, 0, 0);
      acc[1][0] = __builtin_amdgcn_mfma_f32_16x16x32_bf16(af0, f1, acc[1][0], 0, 0, 0);
      acc[1][1] = __builtin_amdgcn_mfma_f32_16x16x32_bf16(af1, f1, acc[1][1], 0, 0, 0);
      acc[2][0] = __builtin_amdgcn_mfma_f32_16x16x32_bf16(ar0, f2, acc[2][0], 0, 0, 0);
      acc[2][1] = __builtin_amdgcn_mfma_f32_16x16x32_bf16(ar1, f2, acc[2][1], 0, 0, 0);
      acc[3][0] = __builtin_amdgcn_mfma_f32_16x16x32_bf16(ar0, f3, acc[3][0], 0, 0, 0);
      acc[3][1] = __builtin_amdgcn_mfma_f32_16x16x32_bf16(ar1, f3, acc[3][1], 0, 0, 0);
    }
  }

  {
    int n = n0 + wn * 16 + c;
    float b0 = bfh[n], b1 = bfg[n], b2 = brh[n], b3 = brg[n];
#pragma unroll
    for (int m = 0; m < 2; m++) {
      int t0 = m0 + wm * 32 + m * 16 + quad * 4;
#pragma unroll
      for (int r = 0; r < 4; r++) {
        int t = t0 + r;
        float Ff = acc[0][m][r] + b0;
        float Gf = 1.0f / (1.0f + __expf(-(acc[1][m][r] + b1)));
        float Fr = acc[2][m][r] + b2;
        float Gr = 1.0f / (1.0f + __expf(-(acc[3][m][r] + b3)));
        float ef = __expf(Gf), er = __expf(Gr);
        out[(size_t)t * 512 + n] = (Ff * ef + Fr * er) / (ef + er);
      }
    }
  }
}

// ---------------------------------------------------------------------------
// Launch. Workspace (bytes):
//   0: xb 4MB | 4: Qfrag 4MB | 8: Kfrag 4MB | 12: Vfrag 4MB
//   16: Tfb 4MB | 20: Trb 4MB | 24: wt 3.5MB
// ---------------------------------------------------------------------------
extern "C" void kernel_launch(void* const* d_in, const int* in_sizes, int n_in,
                              void* d_out, int out_size, void* d_ws, size_t ws_size,
                              hipStream_t stream) {
  const float* x   = (const float*)d_in[0];
  const float* Wq  = (const float*)d_in[1];
  const float* bq  = (const float*)d_in[2];
  const float* Wk  = (const float*)d_in[3];
  const float* bk  = (const float*)d_in[4];
  const float* Wv  = (const float*)d_in[5];
  const float* bv  = (const float*)d_in[6];
  const float* cw  = (const float*)d_in[7];
  const float* cb  = (const float*)d_in[8];
  const float* Wfh = (const float*)d_in[9];
  const float* bfh = (const float*)d_in[10];
  const float* Wfg = (const float*)d_in[11];
  const float* bfg = (const float*)d_in[12];
  const float* Wrh = (const float*)d_in[13];
  const float* brh = (const float*)d_in[14];
  const float* Wrg = (const float*)d_in[15];
  const float* brg = (const float*)d_in[16];

  char* ws = (char*)d_ws;
  const size_t MB = 1024 * 1024;
  unsigned short* xb    = (unsigned short*)(ws + 0 * MB);
  unsigned short* Qfrag = (unsigned short*)(ws + 4 * MB);
  unsigned short* Kfrag = (unsigned short*)(ws + 8 * MB);
  unsigned short* Vfrag = (unsigned short*)(ws + 12 * MB);
  unsigned short* Tfb   = (unsigned short*)(ws + 16 * MB);
  unsigned short* Trb   = (unsigned short*)(ws + 20 * MB);
  unsigned short* wt    = (unsigned short*)(ws + 24 * MB);
  const size_t WSZ = 512 * 512;

  prep_kernel<<<704, 256, 0, stream>>>(x, Wq, Wk, Wv, Wfh, Wfg, Wrh, Wrg, xb, wt);
  qkv_kernel<<<dim3(8, 64), 256, 0, stream>>>(xb, wt + 0 * WSZ, wt + 1 * WSZ, wt + 2 * WSZ,
                                              bq, bk, bv, Qfrag, Kfrag, Vfrag);
  attn_kernel<<<dim3(4, 64), 512, 0, stream>>>(Qfrag, Kfrag, Vfrag, cw, cb, Tfb, Trb);
  final_kernel<<<dim3(16, 64), 256, 0, stream>>>(Tfb, Trb, wt + 3 * WSZ, wt + 4 * WSZ,
                                                 wt + 5 * WSZ, wt + 6 * WSZ,
                                                 bfh, bfg, brh, brg, (float*)d_out);
}